// Round 7
// baseline (198.569 us; speedup 1.0000x reference)
//
#include <hip/hip_runtime.h>
#include <hip/hip_bf16.h>

#define NNODES 50000
#define IN_DIM 256
#define OUT_DIM 128
#define SCALE 1.8f
#define ALPHA 0.15f
#define DSTRIDE 64      // fixed CSR stride; P(deg>64) ~ 2e-21 for Poisson(12)
#define GEMM_BLOCKS 782 // ceil(50000/64)

typedef unsigned short ushort_t;
typedef __attribute__((ext_vector_type(8))) _Float16 f16x8;
typedef __attribute__((ext_vector_type(4))) float f32x4;

// ---------------- helpers ----------------

__device__ __forceinline__ unsigned short f2bf_rne(float f) {
    unsigned int u = __float_as_uint(f);
    unsigned int r = u + 0x7fffu + ((u >> 16) & 1u);  // round-to-nearest-even
    return (unsigned short)(r >> 16);
}

__device__ __forceinline__ float2 bf2_to_f2(unsigned int p) {
    float2 f;
    f.x = __uint_as_float(p << 16);
    f.y = __uint_as_float(p & 0xffff0000u);
    return f;
}

__device__ __forceinline__ unsigned int f2_to_bf2(float x, float y) {
    return (unsigned int)f2bf_rne(x) | ((unsigned int)f2bf_rne(y) << 16);
}

__device__ __forceinline__ unsigned short f2h(float f) {
    _Float16 h = (_Float16)f;  // RNE
    return *(unsigned short*)&h;
}

// ---------------- fused GEMM+norm (blocks 0..781) and CSR fill (blocks 782..) ----
// fill and gemm are independent because gemm now stores the UNSCALED state
// u0 = SCALE * normalize(xW^T + b); the dinv scaling moved into gather round 1
// (dinv[r] = rsqrt(cnt[r]+1), a 16-lane broadcast load from the L2-hot 200 KB
// cnt array). Heterogeneous fusion: fill's latency-bound atomics overlap with
// gemm's compute -> cost ~ max instead of sum. W is converted f32->fp16
// in-register (no init kernel, no Whf buffer).
// GEMM: C/D layout col = lane&15, row = (lane>>4)*4 + reg  [m89-verified];
//       A layout  A[m = lane&15][k = (lane>>4)*8 + j]      [m120-verified].

#define XPAD 264  // 256 + 8 halfs; row stride 528 B (16B-aligned)

__global__ void __launch_bounds__(256, 4) prep_gemm_kernel(
        const float* __restrict__ x, const float* __restrict__ W,
        const float* __restrict__ b,
        const int* __restrict__ row, const int* __restrict__ col, int E,
        int* __restrict__ cnt, ushort_t* __restrict__ csr16,
        ushort_t* __restrict__ u0b) {
    __shared__ __align__(16) ushort_t xh[64][XPAD];

    if (blockIdx.x >= GEMM_BLOCKS) {
        // ---- fill part: single-pass fixed-stride CSR build, 2 edges/thread ----
        int e0 = ((blockIdx.x - GEMM_BLOCKS) * 256 + threadIdx.x) * 2;
        if (e0 < E) {  // E is even; pairs are whole
            int2 rr = *(const int2*)(row + e0);
            int2 cc = *(const int2*)(col + e0);
            int p0 = atomicAdd(&cnt[cc.x], 1);
            if (p0 < DSTRIDE) csr16[(size_t)cc.x * DSTRIDE + p0] = (ushort_t)rr.x;
            int p1 = atomicAdd(&cnt[cc.y], 1);
            if (p1 < DSTRIDE) csr16[(size_t)cc.y * DSTRIDE + p1] = (ushort_t)rr.y;
        }
        return;
    }

    // ---- gemm part ----
    const int t = threadIdx.x;
    const int wv = t >> 6;
    const int lane = t & 63;
    const int q = lane >> 4;     // quad 0..3
    const int c = lane & 15;
    const int rowBase = blockIdx.x * 64;

    // W fragment preload, f32 -> fp16 in-register (W is L2-hot after 1st block)
    f16x8 wf[2][8];
    float bias[2];
    #pragma unroll
    for (int j = 0; j < 2; ++j) {
        const size_t base = (size_t)((2 * wv + j) * 16 + c) * IN_DIM + q * 8;
        #pragma unroll
        for (int kt = 0; kt < 8; ++kt) {
            float4 w0 = *(const float4*)(W + base + kt * 32);
            float4 w1 = *(const float4*)(W + base + kt * 32 + 4);
            f16x8 wp;
            wp[0] = (_Float16)w0.x; wp[1] = (_Float16)w0.y;
            wp[2] = (_Float16)w0.z; wp[3] = (_Float16)w0.w;
            wp[4] = (_Float16)w1.x; wp[5] = (_Float16)w1.y;
            wp[6] = (_Float16)w1.z; wp[7] = (_Float16)w1.w;
            wf[j][kt] = wp;
        }
        bias[j] = b[(2 * wv + j) * 16 + c];
    }

    // stage x (64 rows x 256 k), fp32 -> fp16
    #pragma unroll
    for (int it = 0; it < 16; ++it) {
        int s = it * 256 + t;       // float4 slot
        int r = s >> 6;             // row 0..63
        int ks = (s & 63) * 4;      // k 0..252
        int grow = rowBase + r;
        float4 v = make_float4(0.f, 0.f, 0.f, 0.f);
        if (grow < NNODES) v = *(const float4*)(x + (size_t)grow * IN_DIM + ks);
        uint2 p;
        p.x = (unsigned int)f2h(v.x) | ((unsigned int)f2h(v.y) << 16);
        p.y = (unsigned int)f2h(v.z) | ((unsigned int)f2h(v.w) << 16);
        *(uint2*)&xh[r][ks] = p;
    }
    __syncthreads();

    // MFMA main loop: only LDS reads + MFMAs
    f32x4 acc[4][2];
    #pragma unroll
    for (int m = 0; m < 4; ++m)
        #pragma unroll
        for (int j = 0; j < 2; ++j) {
            acc[m][j][0] = bias[j]; acc[m][j][1] = bias[j];
            acc[m][j][2] = bias[j]; acc[m][j][3] = bias[j];
        }

    #pragma unroll
    for (int kt = 0; kt < 8; ++kt) {
        const int kb = kt * 32 + q * 8;
        #pragma unroll
        for (int m = 0; m < 4; ++m) {
            f16x8 a = *(const f16x8*)&xh[m * 16 + c][kb];
            #pragma unroll
            for (int j = 0; j < 2; ++j)
                acc[m][j] = __builtin_amdgcn_mfma_f32_16x16x32_f16(a, wf[j][kt], acc[m][j], 0, 0, 0);
        }
    }

    // row L2-norm: butterfly over 16 c-lanes, then cross-wave LDS reduce
    float psum[4][4];
    #pragma unroll
    for (int m = 0; m < 4; ++m)
        #pragma unroll
        for (int r = 0; r < 4; ++r)
            psum[m][r] = acc[m][0][r] * acc[m][0][r] + acc[m][1][r] * acc[m][1][r];
    #pragma unroll
    for (int mask = 1; mask < 16; mask <<= 1)
        #pragma unroll
        for (int m = 0; m < 4; ++m)
            #pragma unroll
            for (int r = 0; r < 4; ++r)
                psum[m][r] += __shfl_xor(psum[m][r], mask);

    __syncthreads();  // done reading xh; reuse as reduction scratch
    float* red = (float*)&xh[0][0];       // red[row*8 + wv], 64*8 floats
    float* scl = red + 64 * 8;            // scl[row], 64 floats
    if (c == 0) {
        #pragma unroll
        for (int m = 0; m < 4; ++m)
            #pragma unroll
            for (int r = 0; r < 4; ++r)
                red[(m * 16 + q * 4 + r) * 8 + wv] = psum[m][r];
    }
    __syncthreads();
    if (t < 64) {
        float s = red[t * 8 + 0] + red[t * 8 + 1] + red[t * 8 + 2] + red[t * 8 + 3];
        scl[t] = SCALE / fmaxf(sqrtf(s), 1e-12f);   // NO dinv here (moved to gather0)
    }
    __syncthreads();

    // store u0 (bf16, [N][128], unscaled by dinv)
    #pragma unroll
    for (int m = 0; m < 4; ++m) {
        #pragma unroll
        for (int r = 0; r < 4; ++r) {
            int lrow = m * 16 + q * 4 + r;
            int grow = rowBase + lrow;
            if (grow < NNODES) {
                float sc = scl[lrow];
                #pragma unroll
                for (int j = 0; j < 2; ++j) {
                    float o = acc[m][j][r] * sc;
                    u0b[(size_t)grow * OUT_DIM + (2 * wv + j) * 16 + c] = f2bf_rne(o);
                }
            }
        }
    }
}

// ---------------- gather propagation: wave-per-node, dwordx4 quarters ----------------
// Full 256-B state rows (2 cache lines per edge, fully used; L3-served — chunked
// L2-residency experiments showed L2 retains ~nothing for random gathers).
// Each 16-lane quarter owns one edge; row loaded with dwordx4 (16 B/lane).
// Round 1 (FINAL=0, sin = u0, unscaled): per-edge scale dr = rsqrt(cnt[r]+1)
//   (16-lane broadcast load, L2-hot); acctot = sum dr*u0[r] + dc*u0[c];
//   store s1 = (1-a)*dc^2*acctot + a*dc*u0[c]   (pre-scaled state)     -> bf16
// Round 2 (FINAL=1, sin = s1, pre-scaled): acctot1 = sum s1[r] + s1[c];
//   out = (1-a)*dc*acctot1 + a*u0[c]                                   -> fp32

template <int FINAL>
__global__ void __launch_bounds__(256) gather_kernel(
        const int* __restrict__ cnt, const ushort_t* __restrict__ csr16,
        const unsigned int* __restrict__ sin, const unsigned int* __restrict__ u0,
        unsigned int* __restrict__ sout_b, float* __restrict__ out_f) {
    const int wv = threadIdx.x >> 6;
    const int lane = threadIdx.x & 63;
    const int qd = lane >> 4;      // quarter 0..3: which edge of the 4-batch
    const int d16 = lane & 15;     // dwordx4 slot within the 256-B row
    const int c = blockIdx.x * 4 + wv;  // grid*4 == NNODES exactly

    const int deg = cnt[c];
    int n = deg;
    if (n > DSTRIDE) n = DSTRIDE;
    int idx = 0;
    if (lane < n) idx = (int)csr16[(size_t)c * DSTRIDE + lane];

    float2 a[4];
    #pragma unroll
    for (int k = 0; k < 4; ++k) a[k] = make_float2(0.f, 0.f);

    int j = 0;
    for (; j + 8 <= n; j += 8) {
        int r0 = __shfl(idx, j + qd);
        int r1 = __shfl(idx, j + 4 + qd);
        float sc0 = 1.0f, sc1 = 1.0f;
        if (!FINAL) {
            sc0 = rsqrtf((float)(cnt[r0] + 1));   // broadcast: 16 lanes same addr
            sc1 = rsqrtf((float)(cnt[r1] + 1));
        }
        uint4 v0 = *(const uint4*)(sin + (size_t)r0 * 64 + d16 * 4);
        uint4 v1 = *(const uint4*)(sin + (size_t)r1 * 64 + d16 * 4);
        {
            float2 f0 = bf2_to_f2(v0.x), f1 = bf2_to_f2(v0.y);
            float2 f2 = bf2_to_f2(v0.z), f3 = bf2_to_f2(v0.w);
            a[0].x += sc0 * f0.x; a[0].y += sc0 * f0.y;
            a[1].x += sc0 * f1.x; a[1].y += sc0 * f1.y;
            a[2].x += sc0 * f2.x; a[2].y += sc0 * f2.y;
            a[3].x += sc0 * f3.x; a[3].y += sc0 * f3.y;
        }
        {
            float2 f0 = bf2_to_f2(v1.x), f1 = bf2_to_f2(v1.y);
            float2 f2 = bf2_to_f2(v1.z), f3 = bf2_to_f2(v1.w);
            a[0].x += sc1 * f0.x; a[0].y += sc1 * f0.y;
            a[1].x += sc1 * f1.x; a[1].y += sc1 * f1.y;
            a[2].x += sc1 * f2.x; a[2].y += sc1 * f2.y;
            a[3].x += sc1 * f3.x; a[3].y += sc1 * f3.y;
        }
    }
    for (; j < n; j += 4) {
        int jj = j + qd;
        int rr = __shfl(idx, (jj < n) ? jj : (n - 1));  // clamped; wave-uniform shuffle
        if (jj < n) {
            float sc = 1.0f;
            if (!FINAL) sc = rsqrtf((float)(cnt[rr] + 1));
            uint4 v = *(const uint4*)(sin + (size_t)rr * 64 + d16 * 4);
            float2 f0 = bf2_to_f2(v.x), f1 = bf2_to_f2(v.y);
            float2 f2 = bf2_to_f2(v.z), f3 = bf2_to_f2(v.w);
            a[0].x += sc * f0.x; a[0].y += sc * f0.y;
            a[1].x += sc * f1.x; a[1].y += sc * f1.y;
            a[2].x += sc * f2.x; a[2].y += sc * f2.y;
            a[3].x += sc * f3.x; a[3].y += sc * f3.y;
        }
    }

    // fold the 4 quarters
    #pragma unroll
    for (int k = 0; k < 4; ++k) {
        a[k].x += __shfl_xor(a[k].x, 16);
        a[k].y += __shfl_xor(a[k].y, 16);
        a[k].x += __shfl_xor(a[k].x, 32);
        a[k].y += __shfl_xor(a[k].y, 32);
    }

    if (qd == 0) {
        // self term + epilogue on lanes 0..15
        const float degp1 = (float)(deg + 1);
        const float dc = rsqrtf(degp1);
        uint4 zc4 = *(const uint4*)(sin + (size_t)c * 64 + d16 * 4);
        float2 zc[4];
        zc[0] = bf2_to_f2(zc4.x); zc[1] = bf2_to_f2(zc4.y);
        zc[2] = bf2_to_f2(zc4.z); zc[3] = bf2_to_f2(zc4.w);
        if (FINAL) {
            // acctot1 = sum s1[r] + s1[c]
            #pragma unroll
            for (int k = 0; k < 4; ++k) {
                a[k].x += zc[k].x;
                a[k].y += zc[k].y;
            }
            uint4 z04 = *(const uint4*)(u0 + (size_t)c * 64 + d16 * 4);
            float2 z0[4];
            z0[0] = bf2_to_f2(z04.x); z0[1] = bf2_to_f2(z04.y);
            z0[2] = bf2_to_f2(z04.z); z0[3] = bf2_to_f2(z04.w);
            float gx = (1.0f - ALPHA) * dc;
            float4 o0, o1;
            o0.x = gx * a[0].x + ALPHA * z0[0].x;
            o0.y = gx * a[0].y + ALPHA * z0[0].y;
            o0.z = gx * a[1].x + ALPHA * z0[1].x;
            o0.w = gx * a[1].y + ALPHA * z0[1].y;
            o1.x = gx * a[2].x + ALPHA * z0[2].x;
            o1.y = gx * a[2].y + ALPHA * z0[2].y;
            o1.z = gx * a[3].x + ALPHA * z0[3].x;
            o1.w = gx * a[3].y + ALPHA * z0[3].y;
            float* p = out_f + (size_t)c * 128 + d16 * 8;
            *(float4*)(p) = o0;
            *(float4*)(p + 4) = o1;
        } else {
            // acctot = sum dr*u0[r] + dc*u0[c]
            #pragma unroll
            for (int k = 0; k < 4; ++k) {
                a[k].x += dc * zc[k].x;
                a[k].y += dc * zc[k].y;
            }
            // s1 = (1-a)*dc^2*acctot + a*dc*u0[c]
            float qc = (1.0f - ALPHA) * dc * dc;
            float ac = ALPHA * dc;
            uint4 w;
            w.x = f2_to_bf2(qc * a[0].x + ac * zc[0].x, qc * a[0].y + ac * zc[0].y);
            w.y = f2_to_bf2(qc * a[1].x + ac * zc[1].x, qc * a[1].y + ac * zc[1].y);
            w.z = f2_to_bf2(qc * a[2].x + ac * zc[2].x, qc * a[2].y + ac * zc[2].y);
            w.w = f2_to_bf2(qc * a[3].x + ac * zc[3].x, qc * a[3].y + ac * zc[3].y);
            *(uint4*)(sout_b + (size_t)c * 64 + d16 * 4) = w;
        }
    }
}

extern "C" void kernel_launch(void* const* d_in, const int* in_sizes, int n_in,
                              void* d_out, int out_size, void* d_ws, size_t ws_size,
                              hipStream_t stream) {
    const float* x  = (const float*)d_in[0];
    const int*   ei = (const int*)d_in[1];
    const float* W  = (const float*)d_in[2];
    const float* b  = (const float*)d_in[3];
    float* out = (float*)d_out;

    int E = in_sizes[1] / 2;
    const int* row = ei;       // sources
    const int* col = ei + E;   // targets

    // workspace layout (all segments 16B-aligned)
    unsigned int* u0b = (unsigned int*)d_ws;            // N*64 u32 (bf16x2, [N][64])
    unsigned int* s1b = u0b + (size_t)NNODES * 64;      // N*64 u32
    int* cnt = (int*)(s1b + (size_t)NNODES * 64);       // 50048 ints (200192 B, %16==0)
    ushort_t* csr16 = (ushort_t*)(cnt + 50048);         // N*DSTRIDE u16 (6.4 MB)

    hipMemsetAsync(cnt, 0, 50048 * sizeof(int), stream);

    int fillBlocks = (E + 511) / 512;   // 2 edges per thread
    prep_gemm_kernel<<<GEMM_BLOCKS + fillBlocks, 256, 0, stream>>>(
        x, W, b, row, col, E, cnt, csr16, (ushort_t*)u0b);

    gather_kernel<0><<<NNODES / 4, 256, 0, stream>>>(cnt, csr16, u0b, u0b, s1b, nullptr);
    gather_kernel<1><<<NNODES / 4, 256, 0, stream>>>(cnt, csr16, s1b, u0b, nullptr, out);
}